// Round 5
// baseline (492.411 us; speedup 1.0000x reference)
//
#include <hip/hip_runtime.h>
#include <math.h>

constexpr int B = 2, S = 2048, D = 1024, H = 16, HD = 64;
constexpr int T = B * S;  // 4096 tokens
constexpr float EPS = 1e-5f;
constexpr float LOG2E = 1.44269504088896340736f;

typedef float f32x4 __attribute__((ext_vector_type(4)));
typedef __bf16 bf16x8 __attribute__((ext_vector_type(8)));
typedef unsigned short u16;

struct alignas(16) u4 { unsigned x, y, z, w; };
struct alignas(8) u2 { unsigned x, y; };

__device__ __forceinline__ u16 f2bf(float f) {
  union { __bf16 h; u16 u; } c;
  c.h = (__bf16)f;  // native RNE convert
  return c.u;
}
__device__ __forceinline__ float bf2f(u16 h) {
  return __uint_as_float(((unsigned)h) << 16);
}
__device__ __forceinline__ unsigned pk2(float a, float b) {
  return (unsigned)f2bf(a) | ((unsigned)f2bf(b) << 16);
}
// 2^x via the native transcendental (inputs are <= 0 here; no range fixup).
__device__ __forceinline__ float fexp2(float x) {
  float r;
  asm("v_exp_f32 %0, %1" : "=v"(r) : "v"(x));
  return r;
}
__device__ __forceinline__ f32x4 MM(bf16x8 a, bf16x8 b, f32x4 c) {
  return __builtin_amdgcn_mfma_f32_16x16x32_bf16(a, b, c, 0, 0, 0);
}
union U16x8 { u4 q; bf16x8 b; };

// ---- 64-col tiles (row = 64 u16 = 8 chunks of 16B), XOR swizzle chunk^(r&7)
__device__ __forceinline__ bf16x8 ld_frag(const u16* lds, int row, int chunk) {
  U16x8 u;
  u.q = *(const u4*)((const char*)lds + row * 128 + ((chunk ^ (row & 7)) * 16));
  return u.b;
}
// stage ITERS*32 rows of 64 u16: linear LDS dest, swizzled GLOBAL source.
template <int ITERS>
__device__ __forceinline__ void stageT(const u16* __restrict__ src, size_t off,
                                       int rstride, u16* lds, int tid) {
  const int lane = tid & 63, w = tid >> 6;
#pragma unroll
  for (int p = 0; p < ITERS; ++p) {
    const int idx = p * 256 + w * 64 + lane;
    const int r = idx >> 3, cc = idx & 7;
    const u16* gp = src + off + (size_t)r * rstride + ((cc ^ (r & 7)) * 8);
    u16* lp = lds + (size_t)(p * 256 + w * 64) * 8;  // wave-uniform base
    __builtin_amdgcn_global_load_lds(
        (const __attribute__((address_space(1))) void*)gp,
        (__attribute__((address_space(3))) void*)lp, 16, 0, 0);
  }
}

// ---- 32-col tiles (row = 32 u16 = 4 chunks of 16B), XOR swizzle chunk^(r&3)
__device__ __forceinline__ bf16x8 ld_frag32(const u16* lds, int row, int chunk) {
  U16x8 u;
  u.q = *(const u4*)((const char*)lds + row * 64 + ((chunk ^ (row & 3)) * 16));
  return u.b;
}
// stage ITERS*64 rows of 32 u16.
template <int ITERS>
__device__ __forceinline__ void stage32(const u16* __restrict__ src, size_t off,
                                        int rstride, u16* lds, int tid) {
  const int lane = tid & 63, w = tid >> 6;
#pragma unroll
  for (int p = 0; p < ITERS; ++p) {
    const int idx = p * 256 + w * 64 + lane;
    const int r = idx >> 2, cc = idx & 3;
    const u16* gp = src + off + (size_t)r * rstride + ((cc ^ (r & 3)) * 8);
    u16* lp = lds + (size_t)(p * 256 + w * 64) * 8;  // wave-uniform base
    __builtin_amdgcn_global_load_lds(
        (const __attribute__((address_space(1))) void*)gp,
        (__attribute__((address_space(3))) void*)lp, 16, 0, 0);
  }
}

// ---------------------------------------------------------------------------
// Split fp32 -> bf16 hi + bf16 lo
// ---------------------------------------------------------------------------
__global__ __launch_bounds__(256) void k_split(const float* __restrict__ src,
                                               u16* __restrict__ hi,
                                               u16* __restrict__ lo, int n4) {
  const int i = blockIdx.x * 256 + threadIdx.x;
  if (i >= n4) return;
  const float4 v = ((const float4*)src)[i];
  u2 hh, ll;
  hh.x = pk2(v.x, v.y);
  hh.y = pk2(v.z, v.w);
  ll.x = pk2(v.x - bf2f((u16)hh.x), v.y - bf2f((u16)(hh.x >> 16)));
  ll.y = pk2(v.z - bf2f((u16)hh.y), v.w - bf2f((u16)(hh.y >> 16)));
  ((u2*)hi)[i] = hh;
  ((u2*)lo)[i] = ll;
}

// ---------------------------------------------------------------------------
// QKV projection: 128x128 tile, BK=32, DOUBLE-BUFFERED 2-phase staging.
// Q pre-scaled by (1/8)*log2(e).  V written transposed [B,H,HD,S].
// ---------------------------------------------------------------------------
__global__ __launch_bounds__(256, 2) void k_qkv(
    const u16* __restrict__ xh, const u16* __restrict__ xl,
    const u16* __restrict__ wh, const u16* __restrict__ wl,
    const float* __restrict__ bias, u16* __restrict__ Qh, u16* __restrict__ Ql,
    u16* __restrict__ Kh, u16* __restrict__ Kl, u16* __restrict__ Vh,
    u16* __restrict__ Vl) {
  __shared__ u16 Ah[2][4096], Al[2][4096], Bh[2][4096], Bl[2][4096];
  const int tid = threadIdx.x;
  const int w = tid >> 6, lane = tid & 63;
  const int j = lane & 15, g = lane >> 4;
  const int wr = w >> 1, wc = w & 1;
  const int row0 = blockIdx.y * 128;
  const int col0 = blockIdx.x * 128;
  const f32x4 z4 = {0.f, 0.f, 0.f, 0.f};
  f32x4 acc[4][4];
#pragma unroll
  for (int mi = 0; mi < 4; ++mi)
#pragma unroll
    for (int ni = 0; ni < 4; ++ni) acc[mi][ni] = z4;

  stage32<2>(xh, (size_t)row0 * D, D, Ah[0], tid);
  stage32<2>(xl, (size_t)row0 * D, D, Al[0], tid);
  stage32<2>(wh, (size_t)col0 * D, D, Bh[0], tid);
  stage32<2>(wl, (size_t)col0 * D, D, Bl[0], tid);
  __syncthreads();

  for (int t = 0; t < 32; ++t) {
    const int cur = t & 1;
    if (t < 31) {
      const int k0 = (t + 1) * 32;
      stage32<2>(xh, (size_t)row0 * D + k0, D, Ah[cur ^ 1], tid);
      stage32<2>(xl, (size_t)row0 * D + k0, D, Al[cur ^ 1], tid);
      stage32<2>(wh, (size_t)col0 * D + k0, D, Bh[cur ^ 1], tid);
      stage32<2>(wl, (size_t)col0 * D + k0, D, Bl[cur ^ 1], tid);
    }
    bf16x8 afh[4], afl[4], bfh[4], bfl[4];
#pragma unroll
    for (int mi = 0; mi < 4; ++mi) {
      afh[mi] = ld_frag32(Ah[cur], wr * 64 + 16 * mi + j, g);
      afl[mi] = ld_frag32(Al[cur], wr * 64 + 16 * mi + j, g);
    }
#pragma unroll
    for (int ni = 0; ni < 4; ++ni) {
      bfh[ni] = ld_frag32(Bh[cur], wc * 64 + 16 * ni + j, g);
      bfl[ni] = ld_frag32(Bl[cur], wc * 64 + 16 * ni + j, g);
    }
#pragma unroll
    for (int mi = 0; mi < 4; ++mi)
#pragma unroll
      for (int ni = 0; ni < 4; ++ni) {
        acc[mi][ni] = MM(afh[mi], bfh[ni], acc[mi][ni]);
        acc[mi][ni] = MM(afh[mi], bfl[ni], acc[mi][ni]);
        acc[mi][ni] = MM(afl[mi], bfh[ni], acc[mi][ni]);
      }
    __syncthreads();
  }

  const int part = col0 >> 10;  // uniform per block (128 | 1024)
  if (part < 2) {
    const float qsc = (part == 0) ? 0.125f * LOG2E : 1.0f;
    u16* dh = (part == 0) ? Qh : Kh;
    u16* dl = (part == 0) ? Ql : Kl;
#pragma unroll
    for (int ni = 0; ni < 4; ++ni) {
      const int col = col0 + wc * 64 + 16 * ni + j;
      const int h = (col & 1023) >> 6, hd = col & 63;
      const float bv = bias[col];
#pragma unroll
      for (int mi = 0; mi < 4; ++mi)
#pragma unroll
        for (int r = 0; r < 4; ++r) {
          const int tok = row0 + wr * 64 + 16 * mi + 4 * g + r;
          const int bb = tok >> 11, ss = tok & 2047;
          const float v = (acc[mi][ni][r] + bv) * qsc;
          const size_t o = (((size_t)bb * H + h) * S + ss) * HD + hd;
          const u16 hv = f2bf(v);
          dh[o] = hv;
          dl[o] = f2bf(v - bf2f(hv));
        }
    }
  } else {  // V -> [B,H,HD,S]
#pragma unroll
    for (int ni = 0; ni < 4; ++ni) {
      const int col = col0 + wc * 64 + 16 * ni + j;
      const int h = (col & 1023) >> 6, hd = col & 63;
      const float bv = bias[col];
#pragma unroll
      for (int mi = 0; mi < 4; ++mi) {
        const int tok0 = row0 + wr * 64 + 16 * mi + 4 * g;
        const int bb = tok0 >> 11, ss = tok0 & 2047;
        const float v0 = acc[mi][ni][0] + bv, v1 = acc[mi][ni][1] + bv;
        const float v2 = acc[mi][ni][2] + bv, v3 = acc[mi][ni][3] + bv;
        const u16 h0 = f2bf(v0), h1 = f2bf(v1), h2 = f2bf(v2), h3 = f2bf(v3);
        const size_t o = (((size_t)bb * H + h) * HD + hd) * S + ss;
        u2 ph, pl;
        ph.x = (unsigned)h0 | ((unsigned)h1 << 16);
        ph.y = (unsigned)h2 | ((unsigned)h3 << 16);
        pl.x = pk2(v0 - bf2f(h0), v1 - bf2f(h1));
        pl.y = pk2(v2 - bf2f(h2), v3 - bf2f(h3));
        *(u2*)(Vh + o) = ph;
        *(u2*)(Vl + o) = pl;
      }
    }
  }
}

// ---------------------------------------------------------------------------
// Fused flash ctx: QBLK=128, KVBLK=64, DOUBLE-BUFFERED 2-phase K/V staging.
// Swapped QK^T; online softmax in base-2 domain; in-register P redistribution.
// ---------------------------------------------------------------------------
__global__ __launch_bounds__(256, 2) void k_ctx(
    const u16* __restrict__ Qh, const u16* __restrict__ Ql,
    const u16* __restrict__ Kh, const u16* __restrict__ Kl,
    const u16* __restrict__ Vh, const u16* __restrict__ Vl,
    u16* __restrict__ ch, u16* __restrict__ cl, float* __restrict__ mo,
    float* __restrict__ lo) {
  __shared__ u16 Ksh[2][4096], Ksl[2][4096], Vsh[2][4096], Vsl[2][4096];
  const int tid = threadIdx.x;
  const int w = tid >> 6, lane = tid & 63;
  const int j = lane & 15, g = lane >> 4;
  const int q0 = blockIdx.x * 128;
  const int h = blockIdx.y, b = blockIdx.z;
  const size_t hb = (size_t)b * H + h;
  int qr[2];
  qr[0] = q0 + 32 * w + j;
  qr[1] = qr[0] + 16;

  bf16x8 qfh[2][2], qfl[2][2];
#pragma unroll
  for (int s = 0; s < 2; ++s)
#pragma unroll
    for (int kk = 0; kk < 2; ++kk) {
      const size_t o = (hb * S + qr[s]) * HD + kk * 32 + 8 * g;
      U16x8 u;
      u.q = *(const u4*)(Qh + o);
      qfh[s][kk] = u.b;
      u.q = *(const u4*)(Ql + o);
      qfl[s][kk] = u.b;
    }

  const f32x4 z4 = {0.f, 0.f, 0.f, 0.f};
  f32x4 ctxa[2][4];
#pragma unroll
  for (int s = 0; s < 2; ++s)
#pragma unroll
    for (int mf = 0; mf < 4; ++mf) ctxa[s][mf] = z4;
  float m_run[2] = {-INFINITY, -INFINITY};
  float l_run[2] = {0.f, 0.f};

  stageT<2>(Kh, hb * S * HD, HD, Ksh[0], tid);
  stageT<2>(Kl, hb * S * HD, HD, Ksl[0], tid);
  stageT<2>(Vh, hb * HD * S, S, Vsh[0], tid);
  stageT<2>(Vl, hb * HD * S, S, Vsl[0], tid);
  __syncthreads();

  for (int t = 0; t < 32; ++t) {
    const int cur = t & 1;
    if (t < 31) {
      const int k0 = (t + 1) * 64;
      stageT<2>(Kh, (hb * S + k0) * HD, HD, Ksh[cur ^ 1], tid);
      stageT<2>(Kl, (hb * S + k0) * HD, HD, Ksl[cur ^ 1], tid);
      stageT<2>(Vh, hb * HD * S + k0, S, Vsh[cur ^ 1], tid);
      stageT<2>(Vl, hb * HD * S + k0, S, Vsl[cur ^ 1], tid);
    }

    // S^T[key][q] = K * Q^T (3-term split), for both q-sets
    f32x4 st[2][4];
#pragma unroll
    for (int s = 0; s < 2; ++s)
#pragma unroll
      for (int kb = 0; kb < 4; ++kb) st[s][kb] = z4;
#pragma unroll
    for (int kk = 0; kk < 2; ++kk) {
      bf16x8 kh4[4], kl4[4];
#pragma unroll
      for (int kb = 0; kb < 4; ++kb) {
        kh4[kb] = ld_frag(Ksh[cur], 16 * kb + j, kk * 4 + g);
        kl4[kb] = ld_frag(Ksl[cur], 16 * kb + j, kk * 4 + g);
      }
#pragma unroll
      for (int s = 0; s < 2; ++s)
#pragma unroll
        for (int kb = 0; kb < 4; ++kb) {
          st[s][kb] = MM(kh4[kb], qfh[s][kk], st[s][kb]);
          st[s][kb] = MM(kh4[kb], qfl[s][kk], st[s][kb]);
          st[s][kb] = MM(kl4[kb], qfh[s][kk], st[s][kb]);
        }
    }

    U16x8 pbh[2][2], pbl[2][2];
#pragma unroll
    for (int s = 0; s < 2; ++s) {
      float pm = -INFINITY;
#pragma unroll
      for (int kb = 0; kb < 4; ++kb)
#pragma unroll
        for (int r = 0; r < 4; ++r) pm = fmaxf(pm, st[s][kb][r]);
      pm = fmaxf(pm, __shfl_xor(pm, 16));
      pm = fmaxf(pm, __shfl_xor(pm, 32));
      const float m_new = fmaxf(m_run[s], pm);
      const float sc = fexp2(m_run[s] - m_new);
      m_run[s] = m_new;
      float p[4][4];
      float ls = 0.f;
#pragma unroll
      for (int kb = 0; kb < 4; ++kb)
#pragma unroll
        for (int r = 0; r < 4; ++r) {
          p[kb][r] = fexp2(st[s][kb][r] - m_new);
          ls += p[kb][r];
        }
      l_run[s] = l_run[s] * sc + ls;
#pragma unroll
      for (int mf = 0; mf < 4; ++mf) ctxa[s][mf] *= sc;

      unsigned ph[4][2], pl[4][2];
#pragma unroll
      for (int kb = 0; kb < 4; ++kb) {
        const u16 a0 = f2bf(p[kb][0]), a1 = f2bf(p[kb][1]);
        const u16 a2 = f2bf(p[kb][2]), a3 = f2bf(p[kb][3]);
        ph[kb][0] = (unsigned)a0 | ((unsigned)a1 << 16);
        ph[kb][1] = (unsigned)a2 | ((unsigned)a3 << 16);
        pl[kb][0] = pk2(p[kb][0] - bf2f(a0), p[kb][1] - bf2f(a1));
        pl[kb][1] = pk2(p[kb][2] - bf2f(a2), p[kb][3] - bf2f(a3));
      }
      // Redistribute to PV B-operand slots (verified round-2 mapping).
      const int srcA = ((g & 1) << 5) + j;
      const int srcB = srcA + 16;
      const bool hikb = (g >> 1) != 0;
#pragma unroll
      for (int t2 = 0; t2 < 2; ++t2) {
        const unsigned w0a = __shfl(ph[2 * t2][0], srcA),
                       w0b = __shfl(ph[2 * t2 + 1][0], srcA);
        const unsigned w1a = __shfl(ph[2 * t2][1], srcA),
                       w1b = __shfl(ph[2 * t2 + 1][1], srcA);
        const unsigned w2a = __shfl(ph[2 * t2][0], srcB),
                       w2b = __shfl(ph[2 * t2 + 1][0], srcB);
        const unsigned w3a = __shfl(ph[2 * t2][1], srcB),
                       w3b = __shfl(ph[2 * t2 + 1][1], srcB);
        pbh[s][t2].q.x = hikb ? w0b : w0a;
        pbh[s][t2].q.y = hikb ? w1b : w1a;
        pbh[s][t2].q.z = hikb ? w2b : w2a;
        pbh[s][t2].q.w = hikb ? w3b : w3a;
        const unsigned v0a = __shfl(pl[2 * t2][0], srcA),
                       v0b = __shfl(pl[2 * t2 + 1][0], srcA);
        const unsigned v1a = __shfl(pl[2 * t2][1], srcA),
                       v1b = __shfl(pl[2 * t2 + 1][1], srcA);
        const unsigned v2a = __shfl(pl[2 * t2][0], srcB),
                       v2b = __shfl(pl[2 * t2 + 1][0], srcB);
        const unsigned v3a = __shfl(pl[2 * t2][1], srcB),
                       v3b = __shfl(pl[2 * t2 + 1][1], srcB);
        pbl[s][t2].q.x = hikb ? v0b : v0a;
        pbl[s][t2].q.y = hikb ? v1b : v1a;
        pbl[s][t2].q.z = hikb ? v2b : v2a;
        pbl[s][t2].q.w = hikb ? v3b : v3a;
      }
    }

#pragma unroll
    for (int t2 = 0; t2 < 2; ++t2)
#pragma unroll
      for (int mf = 0; mf < 4; ++mf) {
        const bf16x8 vh_ = ld_frag(Vsh[cur], 16 * mf + j, t2 * 4 + g);
        const bf16x8 vl_ = ld_frag(Vsl[cur], 16 * mf + j, t2 * 4 + g);
#pragma unroll
        for (int s = 0; s < 2; ++s) {
          ctxa[s][mf] = MM(vh_, pbh[s][t2].b, ctxa[s][mf]);
          ctxa[s][mf] = MM(vh_, pbl[s][t2].b, ctxa[s][mf]);
          ctxa[s][mf] = MM(vl_, pbh[s][t2].b, ctxa[s][mf]);
        }
      }
    __syncthreads();
  }

#pragma unroll
  for (int s = 0; s < 2; ++s) {
    float lt = l_run[s];
    lt += __shfl_xor(lt, 16);
    lt += __shfl_xor(lt, 32);
    const float inv = 1.0f / lt;
    const int tokg = b * S + qr[s];
#pragma unroll
    for (int mf = 0; mf < 4; ++mf) {
      const int feat = h * HD + 16 * mf + 4 * g;
      const float v0 = ctxa[s][mf][0] * inv, v1 = ctxa[s][mf][1] * inv;
      const float v2 = ctxa[s][mf][2] * inv, v3 = ctxa[s][mf][3] * inv;
      const u16 h0 = f2bf(v0), h1 = f2bf(v1), h2 = f2bf(v2), h3 = f2bf(v3);
      const size_t o = (size_t)tokg * D + feat;
      u2 hh, ll;
      hh.x = (unsigned)h0 | ((unsigned)h1 << 16);
      hh.y = (unsigned)h2 | ((unsigned)h3 << 16);
      ll.x = pk2(v0 - bf2f(h0), v1 - bf2f(h1));
      ll.y = pk2(v2 - bf2f(h2), v3 - bf2f(h3));
      *(u2*)(ch + o) = hh;
      *(u2*)(cl + o) = ll;
    }
    if (g == 0) {
      mo[hb * S + qr[s]] = m_run[s];
      lo[hb * S + qr[s]] = inv;  // store 1/l
    }
  }
}

// ---------------------------------------------------------------------------
// Out projection + bias + residual: 128x128 tile, BK=32, double-buffered.
// ---------------------------------------------------------------------------
__global__ __launch_bounds__(256, 2) void k_oproj(
    const u16* __restrict__ ah_, const u16* __restrict__ al_,
    const u16* __restrict__ wh, const u16* __restrict__ wl,
    const float* __restrict__ bias, const float* __restrict__ x,
    float* __restrict__ y) {
  __shared__ u16 Ah[2][4096], Al[2][4096], Bh[2][4096], Bl[2][4096];
  const int tid = threadIdx.x;
  const int w = tid >> 6, lane = tid & 63;
  const int j = lane & 15, g = lane >> 4;
  const int wr = w >> 1, wc = w & 1;
  const int row0 = blockIdx.y * 128;
  const int col0 = blockIdx.x * 128;
  const f32x4 z4 = {0.f, 0.f, 0.f, 0.f};
  f32x4 acc[4][4];
#pragma unroll
  for (int mi = 0; mi < 4; ++mi)
#pragma unroll
    for (int ni = 0; ni < 4; ++ni) acc[mi][ni] = z4;

  stage32<2>(ah_, (size_t)row0 * D, D, Ah[0], tid);
  stage32<2>(al_, (size_t)row0 * D, D, Al[0], tid);
  stage32<2>(wh, (size_t)col0 * D, D, Bh[0], tid);
  stage32<2>(wl, (size_t)col0 * D, D, Bl[0], tid);
  __syncthreads();

  for (int t = 0; t < 32; ++t) {
    const int cur = t & 1;
    if (t < 31) {
      const int k0 = (t + 1) * 32;
      stage32<2>(ah_, (size_t)row0 * D + k0, D, Ah[cur ^ 1], tid);
      stage32<2>(al_, (size_t)row0 * D + k0, D, Al[cur ^ 1], tid);
      stage32<2>(wh, (size_t)col0 * D + k0, D, Bh[cur ^ 1], tid);
      stage32<2>(wl, (size_t)col0 * D + k0, D, Bl[cur ^ 1], tid);
    }
    bf16x8 afh[4], afl[4], bfh[4], bfl[4];
#pragma unroll
    for (int mi = 0; mi < 4; ++mi) {
      afh[mi] = ld_frag32(Ah[cur], wr * 64 + 16 * mi + j, g);
      afl[mi] = ld_frag32(Al[cur], wr * 64 + 16 * mi + j, g);
    }
#pragma unroll
    for (int ni = 0; ni < 4; ++ni) {
      bfh[ni] = ld_frag32(Bh[cur], wc * 64 + 16 * ni + j, g);
      bfl[ni] = ld_frag32(Bl[cur], wc * 64 + 16 * ni + j, g);
    }
#pragma unroll
    for (int mi = 0; mi < 4; ++mi)
#pragma unroll
      for (int ni = 0; ni < 4; ++ni) {
        acc[mi][ni] = MM(afh[mi], bfh[ni], acc[mi][ni]);
        acc[mi][ni] = MM(afh[mi], bfl[ni], acc[mi][ni]);
        acc[mi][ni] = MM(afl[mi], bfh[ni], acc[mi][ni]);
      }
    __syncthreads();
  }
#pragma unroll
  for (int ni = 0; ni < 4; ++ni) {
    const int col = col0 + wc * 64 + 16 * ni + j;
    const float bv = bias[col];
#pragma unroll
    for (int mi = 0; mi < 4; ++mi)
#pragma unroll
      for (int r = 0; r < 4; ++r) {
        const int tok = row0 + wr * 64 + 16 * mi + 4 * g + r;
        const size_t off = (size_t)tok * D + col;
        y[off] = acc[mi][ni][r] + bv + x[off];
      }
  }
}

// ---------------------------------------------------------------------------
// attn weights (mean over heads): 128q x 64k tile, double-buffered over heads.
// ---------------------------------------------------------------------------
__global__ __launch_bounds__(256, 2) void k_wts(
    const u16* __restrict__ Qh, const u16* __restrict__ Ql,
    const u16* __restrict__ Kh, const u16* __restrict__ Kl,
    const float* __restrict__ mi, const float* __restrict__ li,
    float* __restrict__ attn) {
  __shared__ u16 Ksh[2][4096], Ksl[2][4096];
  const int tid = threadIdx.x;
  const int w = tid >> 6, lane = tid & 63;
  const int j = lane & 15, g = lane >> 4;
  const int k0 = blockIdx.x * 64;
  const int q0 = blockIdx.y * 128;
  const int b = blockIdx.z;
  const f32x4 z4 = {0.f, 0.f, 0.f, 0.f};
  f32x4 wacc[2][4];
#pragma unroll
  for (int s = 0; s < 2; ++s)
#pragma unroll
    for (int nf = 0; nf < 4; ++nf) wacc[s][nf] = z4;

  {
    const size_t hb0 = (size_t)b * H;
    stageT<2>(Kh, (hb0 * S + k0) * HD, HD, Ksh[0], tid);
    stageT<2>(Kl, (hb0 * S + k0) * HD, HD, Ksl[0], tid);
  }
  __syncthreads();

  for (int h = 0; h < H; ++h) {
    const int cur = h & 1;
    const size_t hb = (size_t)b * H + h;
    if (h < H - 1) {
      const size_t hbn = hb + 1;
      stageT<2>(Kh, (hbn * S + k0) * HD, HD, Ksh[cur ^ 1], tid);
      stageT<2>(Kl, (hbn * S + k0) * HD, HD, Ksl[cur ^ 1], tid);
    }
    bf16x8 qfh[2][2], qfl[2][2];
#pragma unroll
    for (int s = 0; s < 2; ++s)
#pragma unroll
      for (int kk = 0; kk < 2; ++kk) {
        const size_t o = (hb * S + q0 + 32 * w + 16 * s + j) * HD + kk * 32 + 8 * g;
        U16x8 u;
        u.q = *(const u4*)(Qh + o);
        qfh[s][kk] = u.b;
        u.q = *(const u4*)(Ql + o);
        qfl[s][kk] = u.b;
      }
    f32x4 sacc[2][4];
#pragma unroll
    for (int s = 0; s < 2; ++s)
#pragma unroll
      for (int nf = 0; nf < 4; ++nf) sacc[s][nf] = z4;
#pragma unroll
    for (int kk = 0; kk < 2; ++kk) {
#pragma unroll
      for (int nf = 0; nf < 4; ++nf) {
        const bf16x8 kh_ = ld_frag(Ksh[cur], 16 * nf + j, kk * 4 + g);
        const bf16x8 kl_ = ld_frag(Ksl[cur], 16 * nf + j, kk * 4 + g);
#pragma unroll
        for (int s = 0; s < 2; ++s) {
          sacc[s][nf] = MM(qfh[s][kk], kh_, sacc[s][nf]);
          sacc[s][nf] = MM(qfh[s][kk], kl_, sacc[s][nf]);
          sacc[s][nf] = MM(qfl[s][kk], kh_, sacc[s][nf]);
        }
      }
    }
#pragma unroll
    for (int s = 0; s < 2; ++s)
#pragma unroll
      for (int r = 0; r < 4; ++r) {
        const size_t o = hb * S + q0 + 32 * w + 16 * s + 4 * g + r;
        const float m = mi[o];
        const float lv = li[o];  // already 1/l
#pragma unroll
        for (int nf = 0; nf < 4; ++nf)
          wacc[s][nf][r] = fmaf(fexp2(sacc[s][nf][r] - m), lv, wacc[s][nf][r]);
      }
    __syncthreads();
  }
  const float ih = 1.0f / (float)H;
#pragma unroll
  for (int s = 0; s < 2; ++s)
#pragma unroll
    for (int nf = 0; nf < 4; ++nf)
#pragma unroll
      for (int r = 0; r < 4; ++r) {
        const size_t row = (size_t)b * S + q0 + 32 * w + 16 * s + 4 * g + r;
        attn[row * S + k0 + 16 * nf + j] = wacc[s][nf][r] * ih;
      }
}

// ---------------------------------------------------------------------------
// In-place LayerNorm (one block per row).
// ---------------------------------------------------------------------------
__global__ __launch_bounds__(256) void k_ln(float* __restrict__ y,
                                            const float* __restrict__ gamma,
                                            const float* __restrict__ beta) {
  const int row = blockIdx.x;
  const int tid = threadIdx.x;
  const float4 v = *reinterpret_cast<const float4*>(&y[(size_t)row * D + tid * 4]);
  float s = v.x + v.y + v.z + v.w;
  float sq = v.x * v.x + v.y * v.y + v.z * v.z + v.w * v.w;
#pragma unroll
  for (int off = 32; off > 0; off >>= 1) {
    s += __shfl_down(s, off);
    sq += __shfl_down(sq, off);
  }
  __shared__ float sm[8];
  const int wid = tid >> 6, lane = tid & 63;
  if (lane == 0) {
    sm[wid] = s;
    sm[4 + wid] = sq;
  }
  __syncthreads();
  s = sm[0] + sm[1] + sm[2] + sm[3];
  sq = sm[4] + sm[5] + sm[6] + sm[7];
  const float mu = s * (1.0f / D);
  const float var = sq * (1.0f / D) - mu * mu;
  const float rstd = rsqrtf(var + EPS);
  const float4 gmv = *reinterpret_cast<const float4*>(&gamma[tid * 4]);
  const float4 btv = *reinterpret_cast<const float4*>(&beta[tid * 4]);
  float4 o;
  o.x = (v.x - mu) * rstd * gmv.x + btv.x;
  o.y = (v.y - mu) * rstd * gmv.y + btv.y;
  o.z = (v.z - mu) * rstd * gmv.z + btv.z;
  o.w = (v.w - mu) * rstd * gmv.w + btv.w;
  *reinterpret_cast<float4*>(&y[(size_t)row * D + tid * 4]) = o;
}

// ---------------------------------------------------------------------------
extern "C" void kernel_launch(void* const* d_in, const int* in_sizes, int n_in,
                              void* d_out, int out_size, void* d_ws,
                              size_t ws_size, hipStream_t stream) {
  const float* x = (const float*)d_in[0];
  const float* inW = (const float*)d_in[1];
  const float* inB = (const float*)d_in[2];
  const float* outW = (const float*)d_in[3];
  const float* outB = (const float*)d_in[4];
  const float* gamma = (const float*)d_in[5];
  const float* beta = (const float*)d_in[6];

  float* out = (float*)d_out;            // [B,S,D] = 4M f32
  float* attn = out + (size_t)T * D;     // [B,S,S] = 8M f32 = 32 MiB

  // Scratch inside the attn region (fully consumed before k_wts writes attn):
  char* ab = (char*)attn;
  u16* xh = (u16*)(ab);
  u16* xl = (u16*)(ab + (8u << 20));
  u16* wih = (u16*)(ab + (16u << 20));
  u16* wil = (u16*)(ab + (22u << 20));
  u16* woh = (u16*)(ab + (28u << 20));
  u16* wol = (u16*)(ab + (30u << 20));
  u16* cth = xh;  // ctx aliases x-split region (x-split dead after k_qkv)
  u16* ctl = xl;

  char* wsb = (char*)d_ws;
  u16* Qh = (u16*)(wsb);
  u16* Ql = (u16*)(wsb + (8u << 20));
  u16* Kh = (u16*)(wsb + (16u << 20));
  u16* Kl = (u16*)(wsb + (24u << 20));
  u16* Vh = (u16*)(wsb + (32u << 20));
  u16* Vl = (u16*)(wsb + (40u << 20));
  float* mo = (float*)(wsb + (48u << 20));
  float* lo = (float*)(wsb + (48u << 20) + 262144);

  k_split<<<4096, 256, 0, stream>>>(x, xh, xl, T * D / 4);
  k_split<<<3072, 256, 0, stream>>>(inW, wih, wil, 3 * D * D / 4);
  k_split<<<1024, 256, 0, stream>>>(outW, woh, wol, D * D / 4);
  k_qkv<<<dim3(24, 32), 256, 0, stream>>>(xh, xl, wih, wil, inB, Qh, Ql, Kh,
                                          Kl, Vh, Vl);
  k_ctx<<<dim3(16, 16, 2), 256, 0, stream>>>(Qh, Ql, Kh, Kl, Vh, Vl, cth, ctl,
                                             mo, lo);
  k_oproj<<<dim3(8, 32), 256, 0, stream>>>(cth, ctl, woh, wol, outB, x, out);
  k_wts<<<dim3(32, 16, 2), 256, 0, stream>>>(Qh, Ql, Kh, Kl, mo, lo, attn);
  k_ln<<<T, 256, 0, stream>>>(out, gamma, beta);
}

// Round 7
// 453.451 us; speedup vs baseline: 1.0859x; 1.0859x over previous
//
#include <hip/hip_runtime.h>
#include <math.h>

constexpr int B = 2, S = 2048, D = 1024, H = 16, HD = 64;
constexpr int T = B * S;  // 4096 tokens
constexpr float EPS = 1e-5f;
constexpr float LOG2E = 1.44269504088896340736f;

typedef float f32x4 __attribute__((ext_vector_type(4)));
typedef __bf16 bf16x8 __attribute__((ext_vector_type(8)));
typedef unsigned short u16;

struct alignas(16) u4 { unsigned x, y, z, w; };
struct alignas(8) u2 { unsigned x, y; };

__device__ __forceinline__ u16 f2bf(float f) {
  union { __bf16 h; u16 u; } c;
  c.h = (__bf16)f;  // native RNE convert
  return c.u;
}
__device__ __forceinline__ float bf2f(u16 h) {
  return __uint_as_float(((unsigned)h) << 16);
}
__device__ __forceinline__ unsigned pk2(float a, float b) {
  return (unsigned)f2bf(a) | ((unsigned)f2bf(b) << 16);
}
// 2^x via the native transcendental (inputs are <= 0 here; no range fixup).
__device__ __forceinline__ float fexp2(float x) {
  float r;
  asm("v_exp_f32 %0, %1" : "=v"(r) : "v"(x));
  return r;
}
__device__ __forceinline__ f32x4 MM(bf16x8 a, bf16x8 b, f32x4 c) {
  return __builtin_amdgcn_mfma_f32_16x16x32_bf16(a, b, c, 0, 0, 0);
}
union U16x8 { u4 q; bf16x8 b; };

// Read one MFMA fragment (8 contiguous k-elems) from a swizzled LDS tile.
// Tile layout: 16B chunk (r,c) stored at byte r*128 + ((c ^ (r&7))*16).
__device__ __forceinline__ bf16x8 ld_frag(const u16* lds, int row, int chunk) {
  U16x8 u;
  u.q = *(const u4*)((const char*)lds + row * 128 + ((chunk ^ (row & 7)) * 16));
  return u.b;
}

// Async-stage ITERS*32 rows of 64 u16: linear LDS dest (conflict-free DMA
// write) with the XOR swizzle applied to the per-lane GLOBAL source address
// so ld_frag's layout holds (m173 pattern).
template <int ITERS>
__device__ __forceinline__ void stageT(const u16* __restrict__ src, size_t off,
                                       int rstride, u16* lds, int tid) {
  const int lane = tid & 63, w = tid >> 6;
#pragma unroll
  for (int p = 0; p < ITERS; ++p) {
    const int idx = p * 256 + w * 64 + lane;
    const int r = idx >> 3, cc = idx & 7;
    const u16* gp = src + off + (size_t)r * rstride + ((cc ^ (r & 7)) * 8);
    u16* lp = lds + (size_t)(p * 256 + w * 64) * 8;  // wave-uniform base
    __builtin_amdgcn_global_load_lds(
        (const __attribute__((address_space(1))) void*)gp,
        (__attribute__((address_space(3))) void*)lp, 16, 0, 0);
  }
}

// ---------------------------------------------------------------------------
// Split fp32 -> bf16 hi + bf16 lo
// ---------------------------------------------------------------------------
__global__ __launch_bounds__(256) void k_split(const float* __restrict__ src,
                                               u16* __restrict__ hi,
                                               u16* __restrict__ lo, int n4) {
  const int i = blockIdx.x * 256 + threadIdx.x;
  if (i >= n4) return;
  const float4 v = ((const float4*)src)[i];
  u2 hh, ll;
  hh.x = pk2(v.x, v.y);
  hh.y = pk2(v.z, v.w);
  ll.x = pk2(v.x - bf2f((u16)hh.x), v.y - bf2f((u16)(hh.x >> 16)));
  ll.y = pk2(v.z - bf2f((u16)hh.y), v.w - bf2f((u16)(hh.y >> 16)));
  ((u2*)hi)[i] = hh;
  ((u2*)lo)[i] = ll;
}

// ---------------------------------------------------------------------------
// QKV projection: 128x128 tile, BK=64, 4 waves (2x2), 3-term split MFMA.
// (round-4 verified structure: single-buffered async staging)
// ---------------------------------------------------------------------------
__global__ __launch_bounds__(256, 2) void k_qkv(
    const u16* __restrict__ xh, const u16* __restrict__ xl,
    const u16* __restrict__ wh, const u16* __restrict__ wl,
    const float* __restrict__ bias, u16* __restrict__ Qh, u16* __restrict__ Ql,
    u16* __restrict__ Kh, u16* __restrict__ Kl, u16* __restrict__ Vh,
    u16* __restrict__ Vl) {
  __shared__ u16 Ah[8192], Al[8192], Bh[8192], Bl[8192];
  const int tid = threadIdx.x;
  const int w = tid >> 6, lane = tid & 63;
  const int j = lane & 15, g = lane >> 4;
  const int wr = w >> 1, wc = w & 1;
  const int row0 = blockIdx.y * 128;
  const int col0 = blockIdx.x * 128;
  const f32x4 z4 = {0.f, 0.f, 0.f, 0.f};
  f32x4 acc[4][4];
#pragma unroll
  for (int mi = 0; mi < 4; ++mi)
#pragma unroll
    for (int ni = 0; ni < 4; ++ni) acc[mi][ni] = z4;

  for (int k0 = 0; k0 < D; k0 += 64) {
    __syncthreads();
    stageT<4>(xh, (size_t)row0 * D + k0, D, Ah, tid);
    stageT<4>(xl, (size_t)row0 * D + k0, D, Al, tid);
    stageT<4>(wh, (size_t)col0 * D + k0, D, Bh, tid);
    stageT<4>(wl, (size_t)col0 * D + k0, D, Bl, tid);
    __syncthreads();
#pragma unroll
    for (int kk = 0; kk < 2; ++kk) {
      bf16x8 afh[4], afl[4], bfh[4], bfl[4];
#pragma unroll
      for (int mi = 0; mi < 4; ++mi) {
        afh[mi] = ld_frag(Ah, wr * 64 + 16 * mi + j, kk * 4 + g);
        afl[mi] = ld_frag(Al, wr * 64 + 16 * mi + j, kk * 4 + g);
      }
#pragma unroll
      for (int ni = 0; ni < 4; ++ni) {
        bfh[ni] = ld_frag(Bh, wc * 64 + 16 * ni + j, kk * 4 + g);
        bfl[ni] = ld_frag(Bl, wc * 64 + 16 * ni + j, kk * 4 + g);
      }
#pragma unroll
      for (int mi = 0; mi < 4; ++mi)
#pragma unroll
        for (int ni = 0; ni < 4; ++ni) {
          acc[mi][ni] = MM(afh[mi], bfh[ni], acc[mi][ni]);
          acc[mi][ni] = MM(afh[mi], bfl[ni], acc[mi][ni]);
          acc[mi][ni] = MM(afl[mi], bfh[ni], acc[mi][ni]);
        }
    }
  }

  const int part = col0 >> 10;  // uniform per block (128 | 1024)
  if (part < 2) {
    const float qsc = (part == 0) ? 0.125f * LOG2E : 1.0f;
    u16* dh = (part == 0) ? Qh : Kh;
    u16* dl = (part == 0) ? Ql : Kl;
#pragma unroll
    for (int ni = 0; ni < 4; ++ni) {
      const int col = col0 + wc * 64 + 16 * ni + j;
      const int h = (col & 1023) >> 6, hd = col & 63;
      const float bv = bias[col];
#pragma unroll
      for (int mi = 0; mi < 4; ++mi)
#pragma unroll
        for (int r = 0; r < 4; ++r) {
          const int tok = row0 + wr * 64 + 16 * mi + 4 * g + r;
          const int bb = tok >> 11, ss = tok & 2047;
          const float v = (acc[mi][ni][r] + bv) * qsc;
          const size_t o = (((size_t)bb * H + h) * S + ss) * HD + hd;
          const u16 hv = f2bf(v);
          dh[o] = hv;
          dl[o] = f2bf(v - bf2f(hv));
        }
    }
  } else {  // V -> [B,H,HD,S]
#pragma unroll
    for (int ni = 0; ni < 4; ++ni) {
      const int col = col0 + wc * 64 + 16 * ni + j;
      const int h = (col & 1023) >> 6, hd = col & 63;
      const float bv = bias[col];
#pragma unroll
      for (int mi = 0; mi < 4; ++mi) {
        const int tok0 = row0 + wr * 64 + 16 * mi + 4 * g;
        const int bb = tok0 >> 11, ss = tok0 & 2047;
        const float v0 = acc[mi][ni][0] + bv, v1 = acc[mi][ni][1] + bv;
        const float v2 = acc[mi][ni][2] + bv, v3 = acc[mi][ni][3] + bv;
        const u16 h0 = f2bf(v0), h1 = f2bf(v1), h2 = f2bf(v2), h3 = f2bf(v3);
        const size_t o = (((size_t)bb * H + h) * HD + hd) * S + ss;
        u2 ph, pl;
        ph.x = (unsigned)h0 | ((unsigned)h1 << 16);
        ph.y = (unsigned)h2 | ((unsigned)h3 << 16);
        pl.x = pk2(v0 - bf2f(h0), v1 - bf2f(h1));
        pl.y = pk2(v2 - bf2f(h2), v3 - bf2f(h3));
        *(u2*)(Vh + o) = ph;
        *(u2*)(Vl + o) = pl;
      }
    }
  }
}

// ---------------------------------------------------------------------------
// Fused flash ctx: QBLK=128, KVBLK=64, single-buffered staging (round-4),
// P redistribution via PER-WAVE LDS round-trip (no barrier, no shuffles).
// ---------------------------------------------------------------------------
__global__ __launch_bounds__(256, 2) void k_ctx(
    const u16* __restrict__ Qh, const u16* __restrict__ Ql,
    const u16* __restrict__ Kh, const u16* __restrict__ Kl,
    const u16* __restrict__ Vh, const u16* __restrict__ Vl,
    u16* __restrict__ ch, u16* __restrict__ cl, float* __restrict__ mo,
    float* __restrict__ lo) {
  __shared__ u16 Ksh[4096], Ksl[4096], Vsh[4096], Vsl[4096];
  __shared__ u16 Ps[16384];  // [wave][s][hi/lo][16 rows x 64 keys]
  const int tid = threadIdx.x;
  const int w = tid >> 6, lane = tid & 63;
  const int j = lane & 15, g = lane >> 4;
  const int q0 = blockIdx.x * 128;
  const int h = blockIdx.y, b = blockIdx.z;
  const size_t hb = (size_t)b * H + h;
  u16* Pw = Ps + w * 4096;  // this wave's 4 x 1024-u16 sub-buffers
  int qr[2];
  qr[0] = q0 + 32 * w + j;
  qr[1] = qr[0] + 16;

  bf16x8 qfh[2][2], qfl[2][2];
#pragma unroll
  for (int s = 0; s < 2; ++s)
#pragma unroll
    for (int kk = 0; kk < 2; ++kk) {
      const size_t o = (hb * S + qr[s]) * HD + kk * 32 + 8 * g;
      U16x8 u;
      u.q = *(const u4*)(Qh + o);
      qfh[s][kk] = u.b;
      u.q = *(const u4*)(Ql + o);
      qfl[s][kk] = u.b;
    }

  const f32x4 z4 = {0.f, 0.f, 0.f, 0.f};
  f32x4 ctxa[2][4];
#pragma unroll
  for (int s = 0; s < 2; ++s)
#pragma unroll
    for (int mf = 0; mf < 4; ++mf) ctxa[s][mf] = z4;
  float m_run[2] = {-INFINITY, -INFINITY};
  float l_run[2] = {0.f, 0.f};

  for (int k0 = 0; k0 < S; k0 += 64) {
    __syncthreads();
    stageT<2>(Kh, (hb * S + k0) * HD, HD, Ksh, tid);
    stageT<2>(Kl, (hb * S + k0) * HD, HD, Ksl, tid);
    stageT<2>(Vh, hb * HD * S + k0, S, Vsh, tid);
    stageT<2>(Vl, hb * HD * S + k0, S, Vsl, tid);
    __syncthreads();

    // S^T[key][q] = K * Q^T (3-term split), for both q-sets
    f32x4 st[2][4];
#pragma unroll
    for (int s = 0; s < 2; ++s)
#pragma unroll
      for (int kb = 0; kb < 4; ++kb) st[s][kb] = z4;
    __builtin_amdgcn_s_setprio(1);
#pragma unroll
    for (int kk = 0; kk < 2; ++kk) {
      bf16x8 kh4[4], kl4[4];
#pragma unroll
      for (int kb = 0; kb < 4; ++kb) {
        kh4[kb] = ld_frag(Ksh, 16 * kb + j, kk * 4 + g);
        kl4[kb] = ld_frag(Ksl, 16 * kb + j, kk * 4 + g);
      }
#pragma unroll
      for (int s = 0; s < 2; ++s)
#pragma unroll
        for (int kb = 0; kb < 4; ++kb) {
          st[s][kb] = MM(kh4[kb], qfh[s][kk], st[s][kb]);
          st[s][kb] = MM(kh4[kb], qfl[s][kk], st[s][kb]);
          st[s][kb] = MM(kl4[kb], qfh[s][kk], st[s][kb]);
        }
    }
    __builtin_amdgcn_s_setprio(0);

    // online softmax + write P (hi/lo) to this wave's LDS P-buffer.
    // Lane (j,g) holds S^T[key=16kb+4g+r][q=j]; store at row j, key columns.
#pragma unroll
    for (int s = 0; s < 2; ++s) {
      float pm = -INFINITY;
#pragma unroll
      for (int kb = 0; kb < 4; ++kb)
#pragma unroll
        for (int r = 0; r < 4; ++r) pm = fmaxf(pm, st[s][kb][r]);
      pm = fmaxf(pm, __shfl_xor(pm, 16));
      pm = fmaxf(pm, __shfl_xor(pm, 32));
      const float m_new = fmaxf(m_run[s], pm);
      const float sc = fexp2(m_run[s] - m_new);
      m_run[s] = m_new;
      float p[4][4];
      float ls = 0.f;
#pragma unroll
      for (int kb = 0; kb < 4; ++kb)
#pragma unroll
        for (int r = 0; r < 4; ++r) {
          p[kb][r] = fexp2(st[s][kb][r] - m_new);
          ls += p[kb][r];
        }
      l_run[s] = l_run[s] * sc + ls;
#pragma unroll
      for (int mf = 0; mf < 4; ++mf) ctxa[s][mf] *= sc;

      u16* ph_b = Pw + s * 2048;        // hi
      u16* pl_b = Pw + s * 2048 + 1024; // lo
#pragma unroll
      for (int kb = 0; kb < 4; ++kb) {
        const int byte =
            j * 128 + (((2 * kb + (g >> 1)) ^ (j & 7)) * 16) + (g & 1) * 8;
        u2 wv;
        wv.x = pk2(p[kb][0], p[kb][1]);
        wv.y = pk2(p[kb][2], p[kb][3]);
        *(u2*)((char*)ph_b + byte) = wv;
        u2 lv2;
        lv2.x = pk2(p[kb][0] - bf2f((u16)wv.x),
                    p[kb][1] - bf2f((u16)(wv.x >> 16)));
        lv2.y = pk2(p[kb][2] - bf2f((u16)wv.y),
                    p[kb][3] - bf2f((u16)(wv.y >> 16)));
        *(u2*)((char*)pl_b + byte) = lv2;
      }
    }

    // PV: B-frag for lane (j,g) = P^T[keys 32*t2+8g..+7][q=j] straight from
    // the wave-private LDS buffer (same ld_frag mapping; no barrier needed).
    __builtin_amdgcn_s_setprio(1);
#pragma unroll
    for (int t2 = 0; t2 < 2; ++t2) {
      bf16x8 pb0h = ld_frag(Pw, j, 4 * t2 + g);
      bf16x8 pb0l = ld_frag(Pw + 1024, j, 4 * t2 + g);
      bf16x8 pb1h = ld_frag(Pw + 2048, j, 4 * t2 + g);
      bf16x8 pb1l = ld_frag(Pw + 3072, j, 4 * t2 + g);
#pragma unroll
      for (int mf = 0; mf < 4; ++mf) {
        const bf16x8 vh_ = ld_frag(Vsh, 16 * mf + j, t2 * 4 + g);
        const bf16x8 vl_ = ld_frag(Vsl, 16 * mf + j, t2 * 4 + g);
        ctxa[0][mf] = MM(vh_, pb0h, ctxa[0][mf]);
        ctxa[0][mf] = MM(vh_, pb0l, ctxa[0][mf]);
        ctxa[0][mf] = MM(vl_, pb0h, ctxa[0][mf]);
        ctxa[1][mf] = MM(vh_, pb1h, ctxa[1][mf]);
        ctxa[1][mf] = MM(vh_, pb1l, ctxa[1][mf]);
        ctxa[1][mf] = MM(vl_, pb1h, ctxa[1][mf]);
      }
    }
    __builtin_amdgcn_s_setprio(0);
  }

#pragma unroll
  for (int s = 0; s < 2; ++s) {
    float lt = l_run[s];
    lt += __shfl_xor(lt, 16);
    lt += __shfl_xor(lt, 32);
    const float inv = 1.0f / lt;
    const int tokg = b * S + qr[s];
#pragma unroll
    for (int mf = 0; mf < 4; ++mf) {
      const int feat = h * HD + 16 * mf + 4 * g;
      const float v0 = ctxa[s][mf][0] * inv, v1 = ctxa[s][mf][1] * inv;
      const float v2 = ctxa[s][mf][2] * inv, v3 = ctxa[s][mf][3] * inv;
      const u16 h0 = f2bf(v0), h1 = f2bf(v1), h2 = f2bf(v2), h3 = f2bf(v3);
      const size_t o = (size_t)tokg * D + feat;
      u2 hh, ll;
      hh.x = (unsigned)h0 | ((unsigned)h1 << 16);
      hh.y = (unsigned)h2 | ((unsigned)h3 << 16);
      ll.x = pk2(v0 - bf2f(h0), v1 - bf2f(h1));
      ll.y = pk2(v2 - bf2f(h2), v3 - bf2f(h3));
      *(u2*)(ch + o) = hh;
      *(u2*)(cl + o) = ll;
    }
    if (g == 0) {
      mo[hb * S + qr[s]] = m_run[s];
      lo[hb * S + qr[s]] = inv;  // store 1/l
    }
  }
}

// ---------------------------------------------------------------------------
// Out projection + bias + residual: 128x128 tile, 3-term split (round-4).
// ---------------------------------------------------------------------------
__global__ __launch_bounds__(256, 2) void k_oproj(
    const u16* __restrict__ ah_, const u16* __restrict__ al_,
    const u16* __restrict__ wh, const u16* __restrict__ wl,
    const float* __restrict__ bias, const float* __restrict__ x,
    float* __restrict__ y) {
  __shared__ u16 Ah[8192], Al[8192], Bh[8192], Bl[8192];
  const int tid = threadIdx.x;
  const int w = tid >> 6, lane = tid & 63;
  const int j = lane & 15, g = lane >> 4;
  const int wr = w >> 1, wc = w & 1;
  const int row0 = blockIdx.y * 128;
  const int col0 = blockIdx.x * 128;
  const f32x4 z4 = {0.f, 0.f, 0.f, 0.f};
  f32x4 acc[4][4];
#pragma unroll
  for (int mi = 0; mi < 4; ++mi)
#pragma unroll
    for (int ni = 0; ni < 4; ++ni) acc[mi][ni] = z4;

  for (int k0 = 0; k0 < D; k0 += 64) {
    __syncthreads();
    stageT<4>(ah_, (size_t)row0 * D + k0, D, Ah, tid);
    stageT<4>(al_, (size_t)row0 * D + k0, D, Al, tid);
    stageT<4>(wh, (size_t)col0 * D + k0, D, Bh, tid);
    stageT<4>(wl, (size_t)col0 * D + k0, D, Bl, tid);
    __syncthreads();
#pragma unroll
    for (int kk = 0; kk < 2; ++kk) {
      bf16x8 afh[4], afl[4], bfh[4], bfl[4];
#pragma unroll
      for (int mi = 0; mi < 4; ++mi) {
        afh[mi] = ld_frag(Ah, wr * 64 + 16 * mi + j, kk * 4 + g);
        afl[mi] = ld_frag(Al, wr * 64 + 16 * mi + j, kk * 4 + g);
      }
#pragma unroll
      for (int ni = 0; ni < 4; ++ni) {
        bfh[ni] = ld_frag(Bh, wc * 64 + 16 * ni + j, kk * 4 + g);
        bfl[ni] = ld_frag(Bl, wc * 64 + 16 * ni + j, kk * 4 + g);
      }
#pragma unroll
      for (int mi = 0; mi < 4; ++mi)
#pragma unroll
        for (int ni = 0; ni < 4; ++ni) {
          acc[mi][ni] = MM(afh[mi], bfh[ni], acc[mi][ni]);
          acc[mi][ni] = MM(afh[mi], bfl[ni], acc[mi][ni]);
          acc[mi][ni] = MM(afl[mi], bfh[ni], acc[mi][ni]);
        }
    }
  }
#pragma unroll
  for (int ni = 0; ni < 4; ++ni) {
    const int col = col0 + wc * 64 + 16 * ni + j;
    const float bv = bias[col];
#pragma unroll
    for (int mi = 0; mi < 4; ++mi)
#pragma unroll
      for (int r = 0; r < 4; ++r) {
        const int tok = row0 + wr * 64 + 16 * mi + 4 * g + r;
        const size_t off = (size_t)tok * D + col;
        y[off] = acc[mi][ni][r] + bv + x[off];
      }
  }
}

// ---------------------------------------------------------------------------
// attn weights (mean over heads): 128q x 64k tile (round-4).
// ---------------------------------------------------------------------------
__global__ __launch_bounds__(256, 2) void k_wts(
    const u16* __restrict__ Qh, const u16* __restrict__ Ql,
    const u16* __restrict__ Kh, const u16* __restrict__ Kl,
    const float* __restrict__ mi, const float* __restrict__ li,
    float* __restrict__ attn) {
  __shared__ u16 Ksh[4096], Ksl[4096];
  const int tid = threadIdx.x;
  const int w = tid >> 6, lane = tid & 63;
  const int j = lane & 15, g = lane >> 4;
  const int k0 = blockIdx.x * 64;
  const int q0 = blockIdx.y * 128;
  const int b = blockIdx.z;
  const f32x4 z4 = {0.f, 0.f, 0.f, 0.f};
  f32x4 wacc[2][4];
#pragma unroll
  for (int s = 0; s < 2; ++s)
#pragma unroll
    for (int nf = 0; nf < 4; ++nf) wacc[s][nf] = z4;

  for (int h = 0; h < H; ++h) {
    const size_t hb = (size_t)b * H + h;
    __syncthreads();
    stageT<2>(Kh, (hb * S + k0) * HD, HD, Ksh, tid);
    stageT<2>(Kl, (hb * S + k0) * HD, HD, Ksl, tid);
    __syncthreads();
    bf16x8 qfh[2][2], qfl[2][2];
#pragma unroll
    for (int s = 0; s < 2; ++s)
#pragma unroll
      for (int kk = 0; kk < 2; ++kk) {
        const size_t o = (hb * S + q0 + 32 * w + 16 * s + j) * HD + kk * 32 + 8 * g;
        U16x8 u;
        u.q = *(const u4*)(Qh + o);
        qfh[s][kk] = u.b;
        u.q = *(const u4*)(Ql + o);
        qfl[s][kk] = u.b;
      }
    f32x4 sacc[2][4];
#pragma unroll
    for (int s = 0; s < 2; ++s)
#pragma unroll
      for (int nf = 0; nf < 4; ++nf) sacc[s][nf] = z4;
#pragma unroll
    for (int kk = 0; kk < 2; ++kk) {
#pragma unroll
      for (int nf = 0; nf < 4; ++nf) {
        const bf16x8 kh_ = ld_frag(Ksh, 16 * nf + j, kk * 4 + g);
        const bf16x8 kl_ = ld_frag(Ksl, 16 * nf + j, kk * 4 + g);
#pragma unroll
        for (int s = 0; s < 2; ++s) {
          sacc[s][nf] = MM(qfh[s][kk], kh_, sacc[s][nf]);
          sacc[s][nf] = MM(qfh[s][kk], kl_, sacc[s][nf]);
          sacc[s][nf] = MM(qfl[s][kk], kh_, sacc[s][nf]);
        }
      }
    }
#pragma unroll
    for (int s = 0; s < 2; ++s)
#pragma unroll
      for (int r = 0; r < 4; ++r) {
        const size_t o = hb * S + q0 + 32 * w + 16 * s + 4 * g + r;
        const float m = mi[o];
        const float lv = li[o];  // already 1/l
#pragma unroll
        for (int nf = 0; nf < 4; ++nf)
          wacc[s][nf][r] = fmaf(fexp2(sacc[s][nf][r] - m), lv, wacc[s][nf][r]);
      }
  }
  const float ih = 1.0f / (float)H;
#pragma unroll
  for (int s = 0; s < 2; ++s)
#pragma unroll
    for (int nf = 0; nf < 4; ++nf)
#pragma unroll
      for (int r = 0; r < 4; ++r) {
        const size_t row = (size_t)b * S + q0 + 32 * w + 16 * s + 4 * g + r;
        attn[row * S + k0 + 16 * nf + j] = wacc[s][nf][r] * ih;
      }
}

// ---------------------------------------------------------------------------
// In-place LayerNorm (one block per row).
// ---------------------------------------------------------------------------
__global__ __launch_bounds__(256) void k_ln(float* __restrict__ y,
                                            const float* __restrict__ gamma,
                                            const float* __restrict__ beta) {
  const int row = blockIdx.x;
  const int tid = threadIdx.x;
  const float4 v = *reinterpret_cast<const float4*>(&y[(size_t)row * D + tid * 4]);
  float s = v.x + v.y + v.z + v.w;
  float sq = v.x * v.x + v.y * v.y + v.z * v.z + v.w * v.w;
#pragma unroll
  for (int off = 32; off > 0; off >>= 1) {
    s += __shfl_down(s, off);
    sq += __shfl_down(sq, off);
  }
  __shared__ float sm[8];
  const int wid = tid >> 6, lane = tid & 63;
  if (lane == 0) {
    sm[wid] = s;
    sm[4 + wid] = sq;
  }
  __syncthreads();
  s = sm[0] + sm[1] + sm[2] + sm[3];
  sq = sm[4] + sm[5] + sm[6] + sm[7];
  const float mu = s * (1.0f / D);
  const float var = sq * (1.0f / D) - mu * mu;
  const float rstd = rsqrtf(var + EPS);
  const float4 gmv = *reinterpret_cast<const float4*>(&gamma[tid * 4]);
  const float4 btv = *reinterpret_cast<const float4*>(&beta[tid * 4]);
  float4 o;
  o.x = (v.x - mu) * rstd * gmv.x + btv.x;
  o.y = (v.y - mu) * rstd * gmv.y + btv.y;
  o.z = (v.z - mu) * rstd * gmv.z + btv.z;
  o.w = (v.w - mu) * rstd * gmv.w + btv.w;
  *reinterpret_cast<float4*>(&y[(size_t)row * D + tid * 4]) = o;
}

// ---------------------------------------------------------------------------
extern "C" void kernel_launch(void* const* d_in, const int* in_sizes, int n_in,
                              void* d_out, int out_size, void* d_ws,
                              size_t ws_size, hipStream_t stream) {
  const float* x = (const float*)d_in[0];
  const float* inW = (const float*)d_in[1];
  const float* inB = (const float*)d_in[2];
  const float* outW = (const float*)d_in[3];
  const float* outB = (const float*)d_in[4];
  const float* gamma = (const float*)d_in[5];
  const float* beta = (const float*)d_in[6];

  float* out = (float*)d_out;            // [B,S,D] = 4M f32
  float* attn = out + (size_t)T * D;     // [B,S,S] = 8M f32 = 32 MiB

  // Scratch inside the attn region (fully consumed before k_wts writes attn):
  char* ab = (char*)attn;
  u16* xh = (u16*)(ab);
  u16* xl = (u16*)(ab + (8u << 20));
  u16* wih = (u16*)(ab + (16u << 20));
  u16* wil = (u16*)(ab + (22u << 20));
  u16* woh = (u16*)(ab + (28u << 20));
  u16* wol = (u16*)(ab + (30u << 20));
  u16* cth = xh;  // ctx aliases x-split region (x-split dead after k_qkv)
  u16* ctl = xl;

  char* wsb = (char*)d_ws;
  u16* Qh = (u16*)(wsb);
  u16* Ql = (u16*)(wsb + (8u << 20));
  u16* Kh = (u16*)(wsb + (16u << 20));
  u16* Kl = (u16*)(wsb + (24u << 20));
  u16* Vh = (u16*)(wsb + (32u << 20));
  u16* Vl = (u16*)(wsb + (40u << 20));
  float* mo = (float*)(wsb + (48u << 20));
  float* lo = (float*)(wsb + (48u << 20) + 262144);

  k_split<<<4096, 256, 0, stream>>>(x, xh, xl, T * D / 4);
  k_split<<<3072, 256, 0, stream>>>(inW, wih, wil, 3 * D * D / 4);
  k_split<<<1024, 256, 0, stream>>>(outW, woh, wol, D * D / 4);
  k_qkv<<<dim3(24, 32), 256, 0, stream>>>(xh, xl, wih, wil, inB, Qh, Ql, Kh,
                                          Kl, Vh, Vl);
  k_ctx<<<dim3(16, 16, 2), 256, 0, stream>>>(Qh, Ql, Kh, Kl, Vh, Vl, cth, ctl,
                                             mo, lo);
  k_oproj<<<dim3(8, 32), 256, 0, stream>>>(cth, ctl, woh, wol, outB, x, out);
  k_wts<<<dim3(32, 16, 2), 256, 0, stream>>>(Qh, Ql, Kh, Kl, mo, lo, attn);
  k_ln<<<T, 256, 0, stream>>>(out, gamma, beta);
}